// Round 5
// baseline (1575.583 us; speedup 1.0000x reference)
//
#include <hip/hip_runtime.h>
#include <hip/hip_bf16.h>
#include <math.h>

#define N_EDGESC  1048576
#define N_GRAPHSC 8192
#define NPG 32     // nodes per graph
#define EPG 128    // edges per graph
#define FXD 78
#define F2C 156
#define F3C 312
#define GHC 156    // Wg1 out
#define GOC 128    // Wg2 out
#define HS  36     // padded node-stride (fp32 k-major tiles)
#define HBS 168    // Hb row stride in shorts (84 dwords; m*84%32 cycles 8 banks)
#define RBK 4      // rows per block in cell/head kernels (4 -> 2048 blocks = 8/CU)
#define GRBK 8     // rows per block in gmlp kernel (8 -> 2048 blocks = 8/CU)

typedef __attribute__((ext_vector_type(8))) short short8v;   // 8 bf16 = 4 VGPR
typedef __attribute__((ext_vector_type(4))) float float4v;

__device__ __forceinline__ short f2bf(float x) {  // RNE truncate f32->bf16 bits
  unsigned u = __float_as_uint(x);
  u += 0x7FFFu + ((u >> 16) & 1u);
  return (short)(u >> 16);
}

// ---------------------------------------------------------------------------
// A-aggregation: reads fp32 k-major H, emits ONLY bf16 node-major Hb[r][k].
template<int FIN, int ROWS>
__device__ __forceinline__ void a_mult_bf(const float* __restrict__ H,
                                          const float* __restrict__ As,
                                          short* __restrict__ Hb, int t) {
  const int r0 = (t & 7) * 4;
  const int g = t >> 3;
  float acc[ROWS][4];
#pragma unroll
  for (int j = 0; j < ROWS; ++j)
    acc[j][0] = acc[j][1] = acc[j][2] = acc[j][3] = 0.f;
#pragma unroll
  for (int c = 0; c < NPG; c += 4) {
    float4 a0 = *(const float4*)(As + (c + 0) * HS + r0);
    float4 a1 = *(const float4*)(As + (c + 1) * HS + r0);
    float4 a2 = *(const float4*)(As + (c + 2) * HS + r0);
    float4 a3 = *(const float4*)(As + (c + 3) * HS + r0);
#pragma unroll
    for (int j = 0; j < ROWS; ++j) {
      int k = g + 32 * j;
      if (k < FIN) {
        float4 h4 = *(const float4*)(H + k * HS + c);
        acc[j][0] = fmaf(h4.x, a0.x, acc[j][0]); acc[j][1] = fmaf(h4.x, a0.y, acc[j][1]);
        acc[j][2] = fmaf(h4.x, a0.z, acc[j][2]); acc[j][3] = fmaf(h4.x, a0.w, acc[j][3]);
        acc[j][0] = fmaf(h4.y, a1.x, acc[j][0]); acc[j][1] = fmaf(h4.y, a1.y, acc[j][1]);
        acc[j][2] = fmaf(h4.y, a1.z, acc[j][2]); acc[j][3] = fmaf(h4.y, a1.w, acc[j][3]);
        acc[j][0] = fmaf(h4.z, a2.x, acc[j][0]); acc[j][1] = fmaf(h4.z, a2.y, acc[j][1]);
        acc[j][2] = fmaf(h4.z, a2.z, acc[j][2]); acc[j][3] = fmaf(h4.z, a2.w, acc[j][3]);
        acc[j][0] = fmaf(h4.w, a3.x, acc[j][0]); acc[j][1] = fmaf(h4.w, a3.y, acc[j][1]);
        acc[j][2] = fmaf(h4.w, a3.z, acc[j][2]); acc[j][3] = fmaf(h4.w, a3.w, acc[j][3]);
      }
    }
  }
#pragma unroll
  for (int j = 0; j < ROWS; ++j) {
    int k = g + 32 * j;
    if (k < FIN) {
#pragma unroll
      for (int i = 0; i < 4; ++i)
        Hb[(r0 + i) * HBS + k] = f2bf(acc[j][i]);
    }
  }
}

// ---------------------------------------------------------------------------
// MFMA mm: D[m][f] = sum_k Hb[m][k] * Wt[f][k] (+bias, relu / pool).
template<int KSTEPS, int NT, int KP, int FOUT, bool POOL>
__device__ __forceinline__ void mm_mfma(const short* __restrict__ Hb,
                                        const short* __restrict__ Wt,
                                        const float* __restrict__ bias,
                                        float* __restrict__ Hout,
                                        unsigned* __restrict__ gmax, int t) {
  const int w = t >> 6;
  const int L = t & 63;
  const int q = L >> 4;
  const int mt = w & 1;                 // wave -> fixed m-tile (A-frag reuse)
  const int m = mt * 16 + (L & 15);
  short8v afrag[KSTEPS];
#pragma unroll
  for (int s = 0; s < KSTEPS; ++s)
    afrag[s] = *(const short8v*)(Hb + m * HBS + s * 32 + q * 8);
  for (int nt = (w >> 1); nt < NT; nt += 2) {
    const int f = nt * 16 + (L & 15);
    float4v acc = {0.f, 0.f, 0.f, 0.f};
#pragma unroll
    for (int s = 0; s < KSTEPS; ++s) {
      short8v bfrag = *(const short8v*)(Wt + (size_t)f * KP + s * 32 + q * 8);
      acc = __builtin_amdgcn_mfma_f32_16x16x32_bf16(afrag[s], bfrag, acc, 0, 0, 0);
    }
    if (f < FOUT) {
      float bb = bias[f];
      float o0 = fmaxf(acc[0] + bb, 0.f), o1 = fmaxf(acc[1] + bb, 0.f);
      float o2 = fmaxf(acc[2] + bb, 0.f), o3 = fmaxf(acc[3] + bb, 0.f);
      if constexpr (POOL) {
        float mx = fmaxf(fmaxf(o0, o1), fmaxf(o2, o3));
        atomicMax(&gmax[f], __float_as_uint(mx));   // relu'd >= 0 -> monotone
      } else {
        float4 o = {o0, o1, o2, o3};
        *(float4*)(Hout + f * HS + mt * 16 + q * 4) = o;
      }
    }
  }
}

// ---------------------------------------------------------------------------
// Weight pre-pack: Wt[f][k] = bf16(W[k][f]), zero-padded to Np x Kp.
__global__ __launch_bounds__(256)
void pack_wt(const float* __restrict__ src, short* __restrict__ dst,
             int FIN, int FOUT, int Kp, int Np) {
  int idx = blockIdx.x * 256 + threadIdx.x;
  if (idx >= Np * Kp) return;
  int f = idx / Kp, k = idx - f * Kp;
  float v = (f < FOUT && k < FIN) ? src[(size_t)k * FOUT + f] : 0.f;
  dst[idx] = f2bf(v);
}

// ---------------------------------------------------------------------------
// One block per graph, blockIdx.y = drug. Ends at the max-pool; graph MLP
// runs in gmlp_kernel. launch_bounds stays (256,3): (256,4) triggers the
// gfx950 arch/accum VGPR split -> 64 arch regs -> spills (R1: +2.5 GB HBM).
__global__ __launch_bounds__(256, 3)
void drug_kernel(const float* __restrict__ x1, const int* __restrict__ ei1,
                 const float* __restrict__ x2, const int* __restrict__ ei2,
                 const short* __restrict__ Wt1, const float* __restrict__ b1,
                 const short* __restrict__ Wt2, const float* __restrict__ b2,
                 const short* __restrict__ Wt3, const float* __restrict__ b3,
                 float* __restrict__ pbuf) {
  __shared__ __align__(16) float X[F2C * HS];    // 22464 B (input + H1 + H2)
  __shared__ __align__(16) float As[NPG * HS];   //  4608 B
  __shared__ __align__(16) short Hb[NPG * HBS];  // 10752 B bf16 node-major
  __shared__ __align__(16) float gbuf[F3C];      //  1248 B (pool target)
  __shared__ __align__(16) float deg[NPG];       //   128 B
  unsigned* gbufU = (unsigned*)gbuf;

  const int t = threadIdx.x;
  const int gid = blockIdx.x;
  const int drug = blockIdx.y;
  const float* __restrict__ x = drug ? x2 : x1;
  const int* __restrict__ ei = drug ? ei2 : ei1;
  const int nbase = gid * NPG;

  // ---- P0: zero deg/As/Hb/gbuf; load x -> regs (pipelined) -> X^T
  if (t < NPG) deg[t] = 0.f;
  for (int i = t; i < NPG * HS; i += 256) As[i] = 0.f;
  for (int i = t; i < NPG * HBS / 2; i += 256) ((int*)Hb)[i] = 0;
  for (int i = t; i < F3C; i += 256) gbufU[i] = 0u;
  const float* xg = x + (size_t)gid * (NPG * FXD);
  float4 xv[3];
#pragma unroll
  for (int j = 0; j < 3; ++j) {
    int idx = t + j * 256;
    if (idx < (NPG * FXD) / 4) xv[j] = ((const float4*)xg)[idx];
  }
  int s = 0, d = 0;
  if (t < EPG) {
    s = ei[(size_t)gid * EPG + t] - nbase;
    d = ei[(size_t)N_EDGESC + (size_t)gid * EPG + t] - nbase;
  }
#pragma unroll
  for (int j = 0; j < 3; ++j) {
    int idx = t + j * 256;
    if (idx < (NPG * FXD) / 4) {
      const float* vp = (const float*)&xv[j];
      int base = idx * 4;
#pragma unroll
      for (int jj = 0; jj < 4; ++jj) {
        int id2 = base + jj;
        int n = id2 / FXD;
        int k = id2 - n * FXD;
        X[k * HS + n] = vp[jj];
      }
    }
  }
  __syncthreads();
  if (t < EPG) atomicAdd(&deg[s], 1.0f);
  __syncthreads();
  if (t < EPG) {
    float w = rsqrtf(deg[s] + 1.0f) * rsqrtf(deg[d] + 1.0f);
    atomicAdd(&As[d * HS + s], w);   // A[s][d]: msg d->s
  }
  if (t < NPG) atomicAdd(&As[t * HS + t], 1.0f / (deg[t] + 1.0f));
  __syncthreads();

  // ---- layer 1: A*x -> Hb ; MFMA (Hb @ Wt1) -> H1 = X rows [FXD..F2C)
  a_mult_bf<FXD, 3>(X, As, Hb, t);
  __syncthreads();
  mm_mfma<3, 5, 96, FXD, false>(Hb, Wt1, b1, X + FXD * HS, nullptr, t);
  __syncthreads();
  // ---- layer 2: reads H1, MFMA overwrites all of X (x input + H1 both dead)
  a_mult_bf<FXD, 3>(X + FXD * HS, As, Hb, t);
  __syncthreads();
  mm_mfma<3, 10, 96, F2C, false>(Hb, Wt2, b2, X, nullptr, t);
  __syncthreads();
  // ---- layer 3 + pool
  a_mult_bf<F2C, 5>(X, As, Hb, t);
  __syncthreads();
  mm_mfma<5, 20, 160, F3C, true>(Hb, Wt3, b3, nullptr, gbufU, t);
  __syncthreads();

  // ---- write pooled vector (gbuf holds relu'd max as float bits)
  const int p = drug * N_GRAPHSC + gid;
  for (int i = t; i < F3C; i += 256) pbuf[(size_t)p * F3C + i] = gbuf[i];
}

// ---------------------------------------------------------------------------
// Batched graph MLP: 16384 pooled rows x (312 ->relu 156 -> 128).
// GRBK=8 -> 2048 blocks (8/CU; weights small so re-read cost ~8 us).
__global__ __launch_bounds__(256, 8)
void gmlp_kernel(const float* __restrict__ pbuf,
                 const float* __restrict__ Wg1, const float* __restrict__ bg1,
                 const float* __restrict__ Wg2, const float* __restrict__ bg2,
                 float* __restrict__ gout) {
  __shared__ __align__(16) float U[F3C * GRBK];   //  9984 B
  __shared__ __align__(16) float H1[GHC * GRBK];  //  4992 B
  const int t = threadIdx.x;
  const int P = blockIdx.x * GRBK;

  for (int i = t; i < (F3C / 4) * GRBK; i += 256) {  // 78*8 = 624
    int r = i / (F3C / 4), c4 = i - r * (F3C / 4);
    float4 v = *(const float4*)(pbuf + (size_t)(P + r) * F3C + c4 * 4);
    int k = c4 * 4;
    U[(k + 0) * GRBK + r] = v.x; U[(k + 1) * GRBK + r] = v.y;
    U[(k + 2) * GRBK + r] = v.z; U[(k + 3) * GRBK + r] = v.w;
  }
  __syncthreads();

  const int r0 = (t & 1) * 4;
  const int f = t >> 1;                 // 0..127
  // layer 1: 312 -> 156 (ff = f, f+128<156)
  float acc[4][2];
#pragma unroll
  for (int i = 0; i < 4; ++i) { acc[i][0] = 0.f; acc[i][1] = 0.f; }
#pragma unroll 4
  for (int k = 0; k < F3C; ++k) {
    float4 h = *(const float4*)(U + k * GRBK + r0);
    const float* wr = Wg1 + (size_t)k * GHC + f;
#pragma unroll
    for (int j = 0; j < 2; ++j) {
      if (f + j * 128 < GHC) {
        float w = wr[j * 128];
        acc[0][j] = fmaf(h.x, w, acc[0][j]);
        acc[1][j] = fmaf(h.y, w, acc[1][j]);
        acc[2][j] = fmaf(h.z, w, acc[2][j]);
        acc[3][j] = fmaf(h.w, w, acc[3][j]);
      }
    }
  }
  __syncthreads();
#pragma unroll
  for (int j = 0; j < 2; ++j) {
    int ff = f + j * 128;
    if (ff < GHC) {
      float bb = bg1[ff];
      float4 o;
      o.x = fmaxf(acc[0][j] + bb, 0.f); o.y = fmaxf(acc[1][j] + bb, 0.f);
      o.z = fmaxf(acc[2][j] + bb, 0.f); o.w = fmaxf(acc[3][j] + bb, 0.f);
      *(float4*)(H1 + ff * GRBK + r0) = o;
    }
  }
  __syncthreads();

  // layer 2: 156 -> 128 (f exactly covers GOC)
  float a2[4];
#pragma unroll
  for (int i = 0; i < 4; ++i) a2[i] = 0.f;
#pragma unroll 4
  for (int k = 0; k < GHC; ++k) {
    float4 h = *(const float4*)(H1 + k * GRBK + r0);
    float w = Wg2[(size_t)k * GOC + f];
    a2[0] = fmaf(h.x, w, a2[0]);
    a2[1] = fmaf(h.y, w, a2[1]);
    a2[2] = fmaf(h.z, w, a2[2]);
    a2[3] = fmaf(h.w, w, a2[3]);
  }
  {
    float bb = bg2[f];
#pragma unroll
    for (int i = 0; i < 4; ++i)
      gout[(size_t)(P + r0 + i) * GOC + f] = a2[i] + bb;
  }
}

// ---------------------------------------------------------------------------
// Cell MLP: RBK=4 rows/block -> 2048 blocks = 8/CU. Each thread: 4 rows x
// 4 cols (f, f+128, f+256, f+384). fp32-only kernel (no AGPR split), so the
// (256,8) VGPR cap of 64 should hold without spills.
__global__ __launch_bounds__(256, 8)
void cell_kernel(const float* __restrict__ cell,
                 const float* __restrict__ Wr1, const float* __restrict__ br1,
                 const float* __restrict__ Wr2, const float* __restrict__ br2,
                 const float* __restrict__ Wr3, const float* __restrict__ br3,
                 float* __restrict__ cout) {
  __shared__ __align__(16) float U[512 * RBK];   // 8192 B
  __shared__ __align__(16) float h2[256 * RBK];  // 4096 B
  const int t = threadIdx.x;
  const int R = blockIdx.x * RBK;
  const int r0 = 0;
  const int f = t;          // wait: 256 threads, N=512 -> f covers via j*256
  // NOTE: remap below uses f = t (0..255), j-stride 256 for layer 1 (512 out),
  // j-stride 0 for layers with N<=256.

  float acc[4][2];          // layer1: rows x {f, f+256}
#pragma unroll
  for (int i = 0; i < 4; ++i) { acc[i][0] = 0.f; acc[i][1] = 0.f; }

  // staging: 4 rows x 250 float4 = 1000 items; items t, t+256, t+512, t+768
  for (int k0 = 0; k0 < 1000; k0 += 200) {
    __syncthreads();
    for (int i = t; i < 200; i += 256) {       // 4 rows x 50 float4 per chunk
      int r = i / 50, k4 = i - r * 50;
      float4 v = *(const float4*)(cell + (size_t)(R + r) * 1000 + k0 + k4 * 4);
      int kk = k4 * 4;
      U[(kk + 0) * RBK + r] = v.x; U[(kk + 1) * RBK + r] = v.y;
      U[(kk + 2) * RBK + r] = v.z; U[(kk + 3) * RBK + r] = v.w;
    }
    __syncthreads();
#pragma unroll 8
    for (int k = 0; k < 200; ++k) {
      float4 h = *(const float4*)(U + k * RBK + r0);
      const float* wr = Wr1 + (size_t)(k0 + k) * 512 + f;
#pragma unroll
      for (int j = 0; j < 2; ++j) {
        float w = wr[j * 256];
        acc[0][j] = fmaf(h.x, w, acc[0][j]);
        acc[1][j] = fmaf(h.y, w, acc[1][j]);
        acc[2][j] = fmaf(h.z, w, acc[2][j]);
        acc[3][j] = fmaf(h.w, w, acc[3][j]);
      }
    }
  }
  __syncthreads();
#pragma unroll
  for (int j = 0; j < 2; ++j) {
    int ff = f + j * 256;
    float bb = br1[ff];
    float4 o;
    o.x = fmaxf(acc[0][j] + bb, 0.f); o.y = fmaxf(acc[1][j] + bb, 0.f);
    o.z = fmaxf(acc[2][j] + bb, 0.f); o.w = fmaxf(acc[3][j] + bb, 0.f);
    *(float4*)(U + ff * RBK + r0) = o;   // U now holds h1: [512][RBK]
  }
  __syncthreads();

  // layer 2: 512 -> 256, f = t (0..255) exactly covers
  float a2[4];
#pragma unroll
  for (int i = 0; i < 4; ++i) a2[i] = 0.f;
#pragma unroll 8
  for (int k = 0; k < 512; ++k) {
    float4 h = *(const float4*)(U + k * RBK + r0);
    float w = Wr2[(size_t)k * 256 + f];
    a2[0] = fmaf(h.x, w, a2[0]);
    a2[1] = fmaf(h.y, w, a2[1]);
    a2[2] = fmaf(h.z, w, a2[2]);
    a2[3] = fmaf(h.w, w, a2[3]);
  }
  {
    float bb = br2[f];
    float4 o;
    o.x = fmaxf(a2[0] + bb, 0.f); o.y = fmaxf(a2[1] + bb, 0.f);
    o.z = fmaxf(a2[2] + bb, 0.f); o.w = fmaxf(a2[3] + bb, 0.f);
    *(float4*)(h2 + f * RBK + r0) = o;
  }
  __syncthreads();

  // layer 3: 256 -> 128, threads t<128 (f = t)
  if (t < 128) {
    float a3[4];
#pragma unroll
    for (int i = 0; i < 4; ++i) a3[i] = 0.f;
#pragma unroll 8
    for (int k = 0; k < 256; ++k) {
      float4 h = *(const float4*)(h2 + k * RBK + r0);
      float w = Wr3[(size_t)k * 128 + t];
      a3[0] = fmaf(h.x, w, a3[0]);
      a3[1] = fmaf(h.y, w, a3[1]);
      a3[2] = fmaf(h.z, w, a3[2]);
      a3[3] = fmaf(h.w, w, a3[3]);
    }
    float bb = br3[t];
#pragma unroll
    for (int i = 0; i < 4; ++i)
      cout[(size_t)(R + i) * GOC + t] = a3[i] + bb;
  }
}

// ---------------------------------------------------------------------------
// Head: RBK=4 rows/block -> 2048 blocks = 8/CU. f = t covers 512 for L1.
__global__ __launch_bounds__(256, 8)
void head_kernel(const float* __restrict__ g1, const float* __restrict__ g2,
                 const float* __restrict__ cc,
                 const float* __restrict__ Wf1, const float* __restrict__ bf1,
                 const float* __restrict__ Wf2, const float* __restrict__ bf2,
                 const float* __restrict__ Wo, const float* __restrict__ bo,
                 const float* __restrict__ pa, float* __restrict__ out) {
  __shared__ __align__(16) float U[512 * RBK];   // 8192 B
  __shared__ __align__(16) float h2[128 * RBK];  // 2048 B
  __shared__ float ssq[RBK];
  __shared__ float scal[RBK];
  __shared__ float red[256];

  const int t = threadIdx.x;
  const int R = blockIdx.x * RBK;
  const int r0 = 0;
  if (t < RBK) ssq[t] = 0.f;
  __syncthreads();
  for (int i = t; i < 96 * RBK; i += 256) {   // 384 items
    int r = i / 96, qq = i - r * 96;
    int col = qq * 4;
    const float* src;
    int c2;
    if (col < 128)      { src = g1; c2 = col; }
    else if (col < 256) { src = g2; c2 = col - 128; }
    else                { src = cc; c2 = col - 256; }
    float4 v = *(const float4*)(src + (size_t)(R + r) * GOC + c2);
    U[(col + 0) * RBK + r] = v.x; U[(col + 1) * RBK + r] = v.y;
    U[(col + 2) * RBK + r] = v.z; U[(col + 3) * RBK + r] = v.w;
    atomicAdd(&ssq[r], v.x * v.x + v.y * v.y + v.z * v.z + v.w * v.w);
  }
  __syncthreads();
  if (t < RBK) scal[t] = 1.0f / fmaxf(sqrtf(ssq[t]), 1e-12f);
  __syncthreads();

  const float a = pa[0];
  const int f = t;   // 0..255, layer1 outputs f and f+256

  float acc[4][2];
#pragma unroll
  for (int i = 0; i < 4; ++i) { acc[i][0] = 0.f; acc[i][1] = 0.f; }
#pragma unroll 8
  for (int k = 0; k < 384; ++k) {
    float4 h = *(const float4*)(U + k * RBK + r0);
    const float* wr = Wf1 + (size_t)k * 512 + f;
#pragma unroll
    for (int j = 0; j < 2; ++j) {
      float w = wr[j * 256];
      acc[0][j] = fmaf(h.x, w, acc[0][j]);
      acc[1][j] = fmaf(h.y, w, acc[1][j]);
      acc[2][j] = fmaf(h.z, w, acc[2][j]);
      acc[3][j] = fmaf(h.w, w, acc[3][j]);
    }
  }
  __syncthreads();
#pragma unroll
  for (int j = 0; j < 2; ++j) {
    int ff = f + j * 256;
    float bb = bf1[ff];
    float4 o;
    float v0 = acc[0][j] * scal[0] + bb; o.x = v0 >= 0.f ? v0 : a * v0;
    float v1 = acc[1][j] * scal[1] + bb; o.y = v1 >= 0.f ? v1 : a * v1;
    float v2 = acc[2][j] * scal[2] + bb; o.z = v2 >= 0.f ? v2 : a * v2;
    float v3 = acc[3][j] * scal[3] + bb; o.w = v3 >= 0.f ? v3 : a * v3;
    *(float4*)(U + ff * RBK + r0) = o;
  }
  __syncthreads();

  // layer 2: 512 -> 128, threads t<128
  if (t < 128) {
    float a2[4];
#pragma unroll
    for (int i = 0; i < 4; ++i) a2[i] = 0.f;
#pragma unroll 8
    for (int k = 0; k < 512; ++k) {
      float4 h = *(const float4*)(U + k * RBK + r0);
      float w = Wf2[(size_t)k * 128 + t];
      a2[0] = fmaf(h.x, w, a2[0]);
      a2[1] = fmaf(h.y, w, a2[1]);
      a2[2] = fmaf(h.z, w, a2[2]);
      a2[3] = fmaf(h.w, w, a2[3]);
    }
    float bb = bf2[t];
#pragma unroll
    for (int i = 0; i < 4; ++i) {
      float v = a2[i] + bb;
      v = v >= 0.f ? v : a * v;
      h2[t * RBK + i] = v;
    }
  }
  __syncthreads();

  {
    int rr = t >> 6, kp = t & 63;   // 4 rows x 64 partial lanes
    float p = 0.f;
#pragma unroll
    for (int jj = 0; jj < 2; ++jj) {
      int k = kp + 64 * jj;
      p = fmaf(h2[k * RBK + rr], Wo[k], p);
    }
    red[t] = p;
  }
  __syncthreads();
  if (t < RBK) {
    float ssum = bo[0];
#pragma unroll
    for (int i = 0; i < 64; ++i) ssum += red[t * 64 + i];
    out[R + t] = 1.0f / (1.0f + expf(-ssum));
  }
}

// ---------------------------------------------------------------------------
extern "C" void kernel_launch(void* const* d_in, const int* in_sizes, int n_in,
                              void* d_out, int out_size, void* d_ws, size_t ws_size,
                              hipStream_t stream) {
  const float* x1  = (const float*)d_in[0];
  const int*   ei1 = (const int*)d_in[1];
  const float* x2  = (const float*)d_in[2];
  const int*   ei2 = (const int*)d_in[3];
  const float* cel = (const float*)d_in[4];
  const float* W1  = (const float*)d_in[7];
  const float* b1  = (const float*)d_in[8];
  const float* W2  = (const float*)d_in[9];
  const float* b2  = (const float*)d_in[10];
  const float* W3  = (const float*)d_in[11];
  const float* b3  = (const float*)d_in[12];
  const float* Wg1 = (const float*)d_in[13];
  const float* bg1 = (const float*)d_in[14];
  const float* Wg2 = (const float*)d_in[15];
  const float* bg2 = (const float*)d_in[16];
  const float* Wr1 = (const float*)d_in[17];
  const float* br1 = (const float*)d_in[18];
  const float* Wr2 = (const float*)d_in[19];
  const float* br2 = (const float*)d_in[20];
  const float* Wr3 = (const float*)d_in[21];
  const float* br3 = (const float*)d_in[22];
  const float* Wf1 = (const float*)d_in[23];
  const float* bf1 = (const float*)d_in[24];
  const float* Wf2 = (const float*)d_in[25];
  const float* bf2 = (const float*)d_in[26];
  const float* Wo  = (const float*)d_in[27];
  const float* bo  = (const float*)d_in[28];
  const float* pa  = (const float*)d_in[29];

  float* ws    = (float*)d_ws;
  float* g1buf = ws;                                   // 8192*128 (drug 0)
  float* g2buf = ws + (size_t)N_GRAPHSC * GOC;         // 8192*128 (drug 1)
  float* cbuf  = ws + (size_t)2 * N_GRAPHSC * GOC;
  short* wt1   = (short*)(ws + (size_t)3 * N_GRAPHSC * GOC);  // 80x96
  short* wt2   = wt1 + 80 * 96;                               // 160x96
  short* wt3   = wt2 + 160 * 96;                               // 320x160
  float* pbuf  = ws + (size_t)3 * N_GRAPHSC * GOC + 37120;     // 16384x312
  float* outp  = (float*)d_out;

  pack_wt<<<dim3((80 * 96 + 255) / 256), dim3(256), 0, stream>>>(W1, wt1, FXD, FXD, 96, 80);
  pack_wt<<<dim3((160 * 96 + 255) / 256), dim3(256), 0, stream>>>(W2, wt2, FXD, F2C, 96, 160);
  pack_wt<<<dim3((320 * 160 + 255) / 256), dim3(256), 0, stream>>>(W3, wt3, F2C, F3C, 160, 320);

  dim3 dgrid(N_GRAPHSC, 2);
  drug_kernel<<<dgrid, dim3(256), 0, stream>>>(
      x1, ei1, x2, ei2, wt1, b1, wt2, b2, wt3, b3, pbuf);
  gmlp_kernel<<<dim3(2 * N_GRAPHSC / GRBK), dim3(256), 0, stream>>>(
      pbuf, Wg1, bg1, Wg2, bg2, g1buf);   // writes both g1buf and g2buf halves
  cell_kernel<<<dim3(N_GRAPHSC / RBK), dim3(256), 0, stream>>>(
      cel, Wr1, br1, Wr2, br2, Wr3, br3, cbuf);
  head_kernel<<<dim3(N_GRAPHSC / RBK), dim3(256), 0, stream>>>(
      g1buf, g2buf, cbuf, Wf1, bf1, Wf2, bf2, Wo, bo, pa, outp);
}

// Round 6
// 1391.227 us; speedup vs baseline: 1.1325x; 1.1325x over previous
//
#include <hip/hip_runtime.h>
#include <hip/hip_bf16.h>
#include <math.h>

#define N_EDGESC  1048576
#define N_GRAPHSC 8192
#define NPG 32     // nodes per graph
#define EPG 128    // edges per graph
#define FXD 78
#define F2C 156
#define F3C 312
#define GHC 156    // Wg1 out
#define GOC 128    // Wg2 out
#define HS  36     // padded node-stride (fp32 k-major tiles)
#define HBS 168    // Hb row stride in shorts (84 dwords; m*84%32 cycles 8 banks)
#define RBK 8      // rows per block in cell/head kernels (R4-proven)
#define GRBK 8     // rows per block in gmlp kernel (8 -> 2048 blocks)

typedef __attribute__((ext_vector_type(8))) short short8v;   // 8 bf16 = 4 VGPR
typedef __attribute__((ext_vector_type(4))) float float4v;

__device__ __forceinline__ short f2bf(float x) {  // RNE truncate f32->bf16 bits
  unsigned u = __float_as_uint(x);
  u += 0x7FFFu + ((u >> 16) & 1u);
  return (short)(u >> 16);
}

// ---------------------------------------------------------------------------
// A-aggregation: reads fp32 k-major H, emits ONLY bf16 node-major Hb[r][k].
// k = KOFS + g + 32j. KOFS split keeps peak live accumulators <= 12 (the
// ROWS=5 version held 20 accs + 13 float4 in flight ~= 84 regs -> spills,
// the phantom 500 MB WRITE_SIZE).
template<int FIN, int ROWS, int KOFS>
__device__ __forceinline__ void a_mult_bf(const float* __restrict__ H,
                                          const float* __restrict__ As,
                                          short* __restrict__ Hb, int t) {
  const int r0 = (t & 7) * 4;
  const int g = t >> 3;
  float acc[ROWS][4];
#pragma unroll
  for (int j = 0; j < ROWS; ++j)
    acc[j][0] = acc[j][1] = acc[j][2] = acc[j][3] = 0.f;
#pragma unroll
  for (int c = 0; c < NPG; c += 4) {
    float4 a0 = *(const float4*)(As + (c + 0) * HS + r0);
    float4 a1 = *(const float4*)(As + (c + 1) * HS + r0);
    float4 a2 = *(const float4*)(As + (c + 2) * HS + r0);
    float4 a3 = *(const float4*)(As + (c + 3) * HS + r0);
#pragma unroll
    for (int j = 0; j < ROWS; ++j) {
      int k = KOFS + g + 32 * j;
      if (k < FIN) {
        float4 h4 = *(const float4*)(H + k * HS + c);
        acc[j][0] = fmaf(h4.x, a0.x, acc[j][0]); acc[j][1] = fmaf(h4.x, a0.y, acc[j][1]);
        acc[j][2] = fmaf(h4.x, a0.z, acc[j][2]); acc[j][3] = fmaf(h4.x, a0.w, acc[j][3]);
        acc[j][0] = fmaf(h4.y, a1.x, acc[j][0]); acc[j][1] = fmaf(h4.y, a1.y, acc[j][1]);
        acc[j][2] = fmaf(h4.y, a1.z, acc[j][2]); acc[j][3] = fmaf(h4.y, a1.w, acc[j][3]);
        acc[j][0] = fmaf(h4.z, a2.x, acc[j][0]); acc[j][1] = fmaf(h4.z, a2.y, acc[j][1]);
        acc[j][2] = fmaf(h4.z, a2.z, acc[j][2]); acc[j][3] = fmaf(h4.z, a2.w, acc[j][3]);
        acc[j][0] = fmaf(h4.w, a3.x, acc[j][0]); acc[j][1] = fmaf(h4.w, a3.y, acc[j][1]);
        acc[j][2] = fmaf(h4.w, a3.z, acc[j][2]); acc[j][3] = fmaf(h4.w, a3.w, acc[j][3]);
      }
    }
  }
#pragma unroll
  for (int j = 0; j < ROWS; ++j) {
    int k = KOFS + g + 32 * j;
    if (k < FIN) {
#pragma unroll
      for (int i = 0; i < 4; ++i)
        Hb[(r0 + i) * HBS + k] = f2bf(acc[j][i]);
    }
  }
}

// ---------------------------------------------------------------------------
// MFMA mm: D[m][f] = sum_k Hb[m][k] * Wt[f][k] (+bias, relu / pool).
template<int KSTEPS, int NT, int KP, int FOUT, bool POOL>
__device__ __forceinline__ void mm_mfma(const short* __restrict__ Hb,
                                        const short* __restrict__ Wt,
                                        const float* __restrict__ bias,
                                        float* __restrict__ Hout,
                                        unsigned* __restrict__ gmax, int t) {
  const int w = t >> 6;
  const int L = t & 63;
  const int q = L >> 4;
  const int mt = w & 1;                 // wave -> fixed m-tile (A-frag reuse)
  const int m = mt * 16 + (L & 15);
  short8v afrag[KSTEPS];
#pragma unroll
  for (int s = 0; s < KSTEPS; ++s)
    afrag[s] = *(const short8v*)(Hb + m * HBS + s * 32 + q * 8);
  for (int nt = (w >> 1); nt < NT; nt += 2) {
    const int f = nt * 16 + (L & 15);
    float4v acc = {0.f, 0.f, 0.f, 0.f};
#pragma unroll
    for (int s = 0; s < KSTEPS; ++s) {
      short8v bfrag = *(const short8v*)(Wt + (size_t)f * KP + s * 32 + q * 8);
      acc = __builtin_amdgcn_mfma_f32_16x16x32_bf16(afrag[s], bfrag, acc, 0, 0, 0);
    }
    if (f < FOUT) {
      float bb = bias[f];
      float o0 = fmaxf(acc[0] + bb, 0.f), o1 = fmaxf(acc[1] + bb, 0.f);
      float o2 = fmaxf(acc[2] + bb, 0.f), o3 = fmaxf(acc[3] + bb, 0.f);
      if constexpr (POOL) {
        float mx = fmaxf(fmaxf(o0, o1), fmaxf(o2, o3));
        atomicMax(&gmax[f], __float_as_uint(mx));   // relu'd >= 0 -> monotone
      } else {
        float4 o = {o0, o1, o2, o3};
        *(float4*)(Hout + f * HS + mt * 16 + q * 4) = o;
      }
    }
  }
}

// ---------------------------------------------------------------------------
// Weight pre-pack: Wt[f][k] = bf16(W[k][f]), zero-padded to Np x Kp.
__global__ __launch_bounds__(256)
void pack_wt(const float* __restrict__ src, short* __restrict__ dst,
             int FIN, int FOUT, int Kp, int Np) {
  int idx = blockIdx.x * 256 + threadIdx.x;
  if (idx >= Np * Kp) return;
  int f = idx / Kp, k = idx - f * Kp;
  float v = (f < FOUT && k < FIN) ? src[(size_t)k * FOUT + f] : 0.f;
  dst[idx] = f2bf(v);
}

// ---------------------------------------------------------------------------
// One block per graph, blockIdx.y = drug. Ends at the max-pool; graph MLP
// runs in gmlp_kernel. launch_bounds stays (256,3): (256,4) triggers the
// gfx950 arch/accum VGPR split -> 64 arch regs -> spills (R1: +2.5 GB HBM).
__global__ __launch_bounds__(256, 3)
void drug_kernel(const float* __restrict__ x1, const int* __restrict__ ei1,
                 const float* __restrict__ x2, const int* __restrict__ ei2,
                 const short* __restrict__ Wt1, const float* __restrict__ b1,
                 const short* __restrict__ Wt2, const float* __restrict__ b2,
                 const short* __restrict__ Wt3, const float* __restrict__ b3,
                 float* __restrict__ pbuf) {
  __shared__ __align__(16) float X[F2C * HS];    // 22464 B (input + H1 + H2)
  __shared__ __align__(16) float As[NPG * HS];   //  4608 B
  __shared__ __align__(16) short Hb[NPG * HBS];  // 10752 B bf16 node-major
  __shared__ __align__(16) float gbuf[F3C];      //  1248 B (pool target)
  __shared__ __align__(16) float deg[NPG];       //   128 B
  unsigned* gbufU = (unsigned*)gbuf;

  const int t = threadIdx.x;
  const int gid = blockIdx.x;
  const int drug = blockIdx.y;
  const float* __restrict__ x = drug ? x2 : x1;
  const int* __restrict__ ei = drug ? ei2 : ei1;
  const int nbase = gid * NPG;

  // ---- P0: zero deg/As/Hb/gbuf; load x -> regs (pipelined) -> X^T
  if (t < NPG) deg[t] = 0.f;
  for (int i = t; i < NPG * HS; i += 256) As[i] = 0.f;
  for (int i = t; i < NPG * HBS / 2; i += 256) ((int*)Hb)[i] = 0;
  for (int i = t; i < F3C; i += 256) gbufU[i] = 0u;
  const float* xg = x + (size_t)gid * (NPG * FXD);
  float4 xv[3];
#pragma unroll
  for (int j = 0; j < 3; ++j) {
    int idx = t + j * 256;
    if (idx < (NPG * FXD) / 4) xv[j] = ((const float4*)xg)[idx];
  }
  int s = 0, d = 0;
  if (t < EPG) {
    s = ei[(size_t)gid * EPG + t] - nbase;
    d = ei[(size_t)N_EDGESC + (size_t)gid * EPG + t] - nbase;
  }
#pragma unroll
  for (int j = 0; j < 3; ++j) {
    int idx = t + j * 256;
    if (idx < (NPG * FXD) / 4) {
      const float* vp = (const float*)&xv[j];
      int base = idx * 4;
#pragma unroll
      for (int jj = 0; jj < 4; ++jj) {
        int id2 = base + jj;
        int n = id2 / FXD;
        int k = id2 - n * FXD;
        X[k * HS + n] = vp[jj];
      }
    }
  }
  __syncthreads();
  if (t < EPG) atomicAdd(&deg[s], 1.0f);
  __syncthreads();
  if (t < EPG) {
    float w = rsqrtf(deg[s] + 1.0f) * rsqrtf(deg[d] + 1.0f);
    atomicAdd(&As[d * HS + s], w);   // A[s][d]: msg d->s
  }
  if (t < NPG) atomicAdd(&As[t * HS + t], 1.0f / (deg[t] + 1.0f));
  __syncthreads();

  // ---- layer 1: A*x -> Hb ; MFMA (Hb @ Wt1) -> H1 = X rows [FXD..F2C)
  a_mult_bf<FXD, 3, 0>(X, As, Hb, t);
  __syncthreads();
  mm_mfma<3, 5, 96, FXD, false>(Hb, Wt1, b1, X + FXD * HS, nullptr, t);
  __syncthreads();
  // ---- layer 2: reads H1, MFMA overwrites all of X (x input + H1 both dead)
  a_mult_bf<FXD, 3, 0>(X + FXD * HS, As, Hb, t);
  __syncthreads();
  mm_mfma<3, 10, 96, F2C, false>(Hb, Wt2, b2, X, nullptr, t);
  __syncthreads();
  // ---- layer 3 + pool: split k-range to cap live accumulators (spill fix)
  a_mult_bf<F2C, 3, 0>(X, As, Hb, t);     // k in [0,96)
  a_mult_bf<F2C, 2, 96>(X, As, Hb, t);    // k in [96,156); disjoint Hb writes
  __syncthreads();
  mm_mfma<5, 20, 160, F3C, true>(Hb, Wt3, b3, nullptr, gbufU, t);
  __syncthreads();

  // ---- write pooled vector (gbuf holds relu'd max as float bits)
  const int p = drug * N_GRAPHSC + gid;
  for (int i = t; i < F3C; i += 256) pbuf[(size_t)p * F3C + i] = gbuf[i];
}

// ---------------------------------------------------------------------------
// Batched graph MLP: 16384 pooled rows x (312 ->relu 156 -> 128).
// GRBK=8 -> 2048 blocks (8/CU; weights small so re-read cost ~8 us).
__global__ __launch_bounds__(256, 8)
void gmlp_kernel(const float* __restrict__ pbuf,
                 const float* __restrict__ Wg1, const float* __restrict__ bg1,
                 const float* __restrict__ Wg2, const float* __restrict__ bg2,
                 float* __restrict__ gout) {
  __shared__ __align__(16) float U[F3C * GRBK];   //  9984 B
  __shared__ __align__(16) float H1[GHC * GRBK];  //  4992 B
  const int t = threadIdx.x;
  const int P = blockIdx.x * GRBK;

  for (int i = t; i < (F3C / 4) * GRBK; i += 256) {  // 78*8 = 624
    int r = i / (F3C / 4), c4 = i - r * (F3C / 4);
    float4 v = *(const float4*)(pbuf + (size_t)(P + r) * F3C + c4 * 4);
    int k = c4 * 4;
    U[(k + 0) * GRBK + r] = v.x; U[(k + 1) * GRBK + r] = v.y;
    U[(k + 2) * GRBK + r] = v.z; U[(k + 3) * GRBK + r] = v.w;
  }
  __syncthreads();

  const int r0 = (t & 1) * 4;
  const int f = t >> 1;                 // 0..127
  // layer 1: 312 -> 156 (ff = f, f+128<156)
  float acc[4][2];
#pragma unroll
  for (int i = 0; i < 4; ++i) { acc[i][0] = 0.f; acc[i][1] = 0.f; }
#pragma unroll 4
  for (int k = 0; k < F3C; ++k) {
    float4 h = *(const float4*)(U + k * GRBK + r0);
    const float* wr = Wg1 + (size_t)k * GHC + f;
#pragma unroll
    for (int j = 0; j < 2; ++j) {
      if (f + j * 128 < GHC) {
        float w = wr[j * 128];
        acc[0][j] = fmaf(h.x, w, acc[0][j]);
        acc[1][j] = fmaf(h.y, w, acc[1][j]);
        acc[2][j] = fmaf(h.z, w, acc[2][j]);
        acc[3][j] = fmaf(h.w, w, acc[3][j]);
      }
    }
  }
  __syncthreads();
#pragma unroll
  for (int j = 0; j < 2; ++j) {
    int ff = f + j * 128;
    if (ff < GHC) {
      float bb = bg1[ff];
      float4 o;
      o.x = fmaxf(acc[0][j] + bb, 0.f); o.y = fmaxf(acc[1][j] + bb, 0.f);
      o.z = fmaxf(acc[2][j] + bb, 0.f); o.w = fmaxf(acc[3][j] + bb, 0.f);
      *(float4*)(H1 + ff * GRBK + r0) = o;
    }
  }
  __syncthreads();

  // layer 2: 156 -> 128 (f exactly covers GOC)
  float a2[4];
#pragma unroll
  for (int i = 0; i < 4; ++i) a2[i] = 0.f;
#pragma unroll 4
  for (int k = 0; k < GHC; ++k) {
    float4 h = *(const float4*)(H1 + k * GRBK + r0);
    float w = Wg2[(size_t)k * GOC + f];
    a2[0] = fmaf(h.x, w, a2[0]);
    a2[1] = fmaf(h.y, w, a2[1]);
    a2[2] = fmaf(h.z, w, a2[2]);
    a2[3] = fmaf(h.w, w, a2[3]);
  }
  {
    float bb = bg2[f];
#pragma unroll
    for (int i = 0; i < 4; ++i)
      gout[(size_t)(P + r0 + i) * GOC + f] = a2[i] + bb;
  }
}

// ---------------------------------------------------------------------------
// Cell MLP (R4-proven): 8 rows/block, 4x4 microtile, unroll 8, async staging.
__global__ __launch_bounds__(256, 4)
void cell_kernel(const float* __restrict__ cell,
                 const float* __restrict__ Wr1, const float* __restrict__ br1,
                 const float* __restrict__ Wr2, const float* __restrict__ br2,
                 const float* __restrict__ Wr3, const float* __restrict__ br3,
                 float* __restrict__ cout) {
  __shared__ __align__(16) float U[512 * RBK];   // 16384 B
  __shared__ __align__(16) float h2[256 * RBK];  //  8192 B
  const int t = threadIdx.x;
  const int R = blockIdx.x * RBK;
  const int r0 = (t & 1) * 4;
  const int f = t >> 1;

  float acc[4][4];
#pragma unroll
  for (int i = 0; i < 4; ++i)
#pragma unroll
    for (int j = 0; j < 4; ++j) acc[i][j] = 0.f;

  // staging indices: item i covers row i/50, float4 i%50 of the 200-col chunk
  const int ra = t / 50, ka = t - ra * 50;           // item t   (always valid)
  const int i2 = t + 256;
  const int rb = i2 / 50, kb = i2 - rb * 50;         // item t+256 (valid t<144)
  float4 va, vb;
  va = *(const float4*)(cell + (size_t)(R + ra) * 1000 + ka * 4);
  if (t < 144) vb = *(const float4*)(cell + (size_t)(R + rb) * 1000 + kb * 4);

  for (int k0 = 0; k0 < 1000; k0 += 200) {
    __syncthreads();     // previous chunk's consumers done with U
    {
      int kk = ka * 4;
      U[(kk + 0) * RBK + ra] = va.x; U[(kk + 1) * RBK + ra] = va.y;
      U[(kk + 2) * RBK + ra] = va.z; U[(kk + 3) * RBK + ra] = va.w;
      if (t < 144) {
        int kk2 = kb * 4;
        U[(kk2 + 0) * RBK + rb] = vb.x; U[(kk2 + 1) * RBK + rb] = vb.y;
        U[(kk2 + 2) * RBK + rb] = vb.z; U[(kk2 + 3) * RBK + rb] = vb.w;
      }
    }
    if (k0 + 200 < 1000) {   // issue next chunk's loads; they fly under compute
      va = *(const float4*)(cell + (size_t)(R + ra) * 1000 + (k0 + 200) + ka * 4);
      if (t < 144)
        vb = *(const float4*)(cell + (size_t)(R + rb) * 1000 + (k0 + 200) + kb * 4);
    }
    __syncthreads();
#pragma unroll 8
    for (int k = 0; k < 200; ++k) {
      float4 h = *(const float4*)(U + k * RBK + r0);
      const float* wr = Wr1 + (size_t)(k0 + k) * 512 + f;
#pragma unroll
      for (int j = 0; j < 4; ++j) {
        float w = wr[j * 128];
        acc[0][j] = fmaf(h.x, w, acc[0][j]);
        acc[1][j] = fmaf(h.y, w, acc[1][j]);
        acc[2][j] = fmaf(h.z, w, acc[2][j]);
        acc[3][j] = fmaf(h.w, w, acc[3][j]);
      }
    }
  }
  __syncthreads();
#pragma unroll
  for (int j = 0; j < 4; ++j) {
    int ff = f + j * 128;
    float bb = br1[ff];
    float4 o;
    o.x = fmaxf(acc[0][j] + bb, 0.f); o.y = fmaxf(acc[1][j] + bb, 0.f);
    o.z = fmaxf(acc[2][j] + bb, 0.f); o.w = fmaxf(acc[3][j] + bb, 0.f);
    *(float4*)(U + ff * RBK + r0) = o;
  }
  __syncthreads();

  float a2[4][2];
#pragma unroll
  for (int i = 0; i < 4; ++i) { a2[i][0] = 0.f; a2[i][1] = 0.f; }
#pragma unroll 8
  for (int k = 0; k < 512; ++k) {
    float4 h = *(const float4*)(U + k * RBK + r0);
    const float* wr = Wr2 + (size_t)k * 256 + f;
#pragma unroll
    for (int j = 0; j < 2; ++j) {
      float w = wr[j * 128];
      a2[0][j] = fmaf(h.x, w, a2[0][j]);
      a2[1][j] = fmaf(h.y, w, a2[1][j]);
      a2[2][j] = fmaf(h.z, w, a2[2][j]);
      a2[3][j] = fmaf(h.w, w, a2[3][j]);
    }
  }
#pragma unroll
  for (int j = 0; j < 2; ++j) {
    int ff = f + j * 128;
    float bb = br2[ff];
    float4 o;
    o.x = fmaxf(a2[0][j] + bb, 0.f); o.y = fmaxf(a2[1][j] + bb, 0.f);
    o.z = fmaxf(a2[2][j] + bb, 0.f); o.w = fmaxf(a2[3][j] + bb, 0.f);
    *(float4*)(h2 + ff * RBK + r0) = o;
  }
  __syncthreads();

  float a3[4];
#pragma unroll
  for (int i = 0; i < 4; ++i) a3[i] = 0.f;
#pragma unroll 8
  for (int k = 0; k < 256; ++k) {
    float4 h = *(const float4*)(h2 + k * RBK + r0);
    float w = Wr3[(size_t)k * 128 + f];
    a3[0] = fmaf(h.x, w, a3[0]);
    a3[1] = fmaf(h.y, w, a3[1]);
    a3[2] = fmaf(h.z, w, a3[2]);
    a3[3] = fmaf(h.w, w, a3[3]);
  }
  {
    float bb = br3[f];
#pragma unroll
    for (int i = 0; i < 4; ++i)
      cout[(size_t)(R + r0 + i) * GOC + f] = a3[i] + bb;
  }
}

// ---------------------------------------------------------------------------
// Head (R4-proven): 8 rows/block, unroll 8 on the two big k-loops.
__global__ __launch_bounds__(256, 4)
void head_kernel(const float* __restrict__ g1, const float* __restrict__ g2,
                 const float* __restrict__ cc,
                 const float* __restrict__ Wf1, const float* __restrict__ bf1,
                 const float* __restrict__ Wf2, const float* __restrict__ bf2,
                 const float* __restrict__ Wo, const float* __restrict__ bo,
                 const float* __restrict__ pa, float* __restrict__ out) {
  __shared__ __align__(16) float U[512 * RBK];   // 16384 B
  __shared__ __align__(16) float h2[128 * RBK];  //  4096 B
  __shared__ float ssq[RBK];
  __shared__ float scal[RBK];
  __shared__ float red[256];

  const int t = threadIdx.x;
  const int R = blockIdx.x * RBK;
  if (t < RBK) ssq[t] = 0.f;
  __syncthreads();
  for (int i = t; i < 96 * RBK; i += 256) {
    int r = i / 96, qq = i - r * 96;
    int col = qq * 4;
    const float* src;
    int c2;
    if (col < 128)      { src = g1; c2 = col; }
    else if (col < 256) { src = g2; c2 = col - 128; }
    else                { src = cc; c2 = col - 256; }
    float4 v = *(const float4*)(src + (size_t)(R + r) * GOC + c2);
    U[(col + 0) * RBK + r] = v.x; U[(col + 1) * RBK + r] = v.y;
    U[(col + 2) * RBK + r] = v.z; U[(col + 3) * RBK + r] = v.w;
    atomicAdd(&ssq[r], v.x * v.x + v.y * v.y + v.z * v.z + v.w * v.w);
  }
  __syncthreads();
  if (t < RBK) scal[t] = 1.0f / fmaxf(sqrtf(ssq[t]), 1e-12f);
  __syncthreads();

  const float a = pa[0];
  const int r0 = (t & 1) * 4;
  const int f = t >> 1;

  float acc[4][4];
#pragma unroll
  for (int i = 0; i < 4; ++i)
#pragma unroll
    for (int j = 0; j < 4; ++j) acc[i][j] = 0.f;
#pragma unroll 8
  for (int k = 0; k < 384; ++k) {
    float4 h = *(const float4*)(U + k * RBK + r0);
    const float* wr = Wf1 + (size_t)k * 512 + f;
#pragma unroll
    for (int j = 0; j < 4; ++j) {
      float w = wr[j * 128];
      acc[0][j] = fmaf(h.x, w, acc[0][j]);
      acc[1][j] = fmaf(h.y, w, acc[1][j]);
      acc[2][j] = fmaf(h.z, w, acc[2][j]);
      acc[3][j] = fmaf(h.w, w, acc[3][j]);
    }
  }
  __syncthreads();
#pragma unroll
  for (int j = 0; j < 4; ++j) {
    int ff = f + j * 128;
    float bb = bf1[ff];
    float4 o;
    float v0 = acc[0][j] * scal[r0 + 0] + bb; o.x = v0 >= 0.f ? v0 : a * v0;
    float v1 = acc[1][j] * scal[r0 + 1] + bb; o.y = v1 >= 0.f ? v1 : a * v1;
    float v2 = acc[2][j] * scal[r0 + 2] + bb; o.z = v2 >= 0.f ? v2 : a * v2;
    float v3 = acc[3][j] * scal[r0 + 3] + bb; o.w = v3 >= 0.f ? v3 : a * v3;
    *(float4*)(U + ff * RBK + r0) = o;
  }
  __syncthreads();

  float a2[4];
#pragma unroll
  for (int i = 0; i < 4; ++i) a2[i] = 0.f;
#pragma unroll 8
  for (int k = 0; k < 512; ++k) {
    float4 h = *(const float4*)(U + k * RBK + r0);
    float w = Wf2[(size_t)k * 128 + f];
    a2[0] = fmaf(h.x, w, a2[0]);
    a2[1] = fmaf(h.y, w, a2[1]);
    a2[2] = fmaf(h.z, w, a2[2]);
    a2[3] = fmaf(h.w, w, a2[3]);
  }
  {
    float bb = bf2[f];
#pragma unroll
    for (int i = 0; i < 4; ++i) {
      float v = a2[i] + bb;
      v = v >= 0.f ? v : a * v;
      h2[f * RBK + (r0 + i)] = v;
    }
  }
  __syncthreads();

  {
    int rr = t >> 5, kp = t & 31;
    float p = 0.f;
#pragma unroll
    for (int jj = 0; jj < 4; ++jj) {
      int k = kp + 32 * jj;
      p = fmaf(h2[k * RBK + rr], Wo[k], p);
    }
    red[t] = p;
  }
  __syncthreads();
  if (t < RBK) {
    float ssum = bo[0];
#pragma unroll
    for (int i = 0; i < 32; ++i) ssum += red[t * 32 + i];
    out[R + t] = 1.0f / (1.0f + expf(-ssum));
  }
}

// ---------------------------------------------------------------------------
extern "C" void kernel_launch(void* const* d_in, const int* in_sizes, int n_in,
                              void* d_out, int out_size, void* d_ws, size_t ws_size,
                              hipStream_t stream) {
  const float* x1  = (const float*)d_in[0];
  const int*   ei1 = (const int*)d_in[1];
  const float* x2  = (const float*)d_in[2];
  const int*   ei2 = (const int*)d_in[3];
  const float* cel = (const float*)d_in[4];
  const float* W1  = (const float*)d_in[7];
  const float* b1  = (const float*)d_in[8];
  const float* W2  = (const float*)d_in[9];
  const float* b2  = (const float*)d_in[10];
  const float* W3  = (const float*)d_in[11];
  const float* b3  = (const float*)d_in[12];
  const float* Wg1 = (const float*)d_in[13];
  const float* bg1 = (const float*)d_in[14];
  const float* Wg2 = (const float*)d_in[15];
  const float* bg2 = (const float*)d_in[16];
  const float* Wr1 = (const float*)d_in[17];
  const float* br1 = (const float*)d_in[18];
  const float* Wr2 = (const float*)d_in[19];
  const float* br2 = (const float*)d_in[20];
  const float* Wr3 = (const float*)d_in[21];
  const float* br3 = (const float*)d_in[22];
  const float* Wf1 = (const float*)d_in[23];
  const float* bf1 = (const float*)d_in[24];
  const float* Wf2 = (const float*)d_in[25];
  const float* bf2 = (const float*)d_in[26];
  const float* Wo  = (const float*)d_in[27];
  const float* bo  = (const float*)d_in[28];
  const float* pa  = (const float*)d_in[29];

  float* ws    = (float*)d_ws;
  float* g1buf = ws;                                   // 8192*128 (drug 0)
  float* g2buf = ws + (size_t)N_GRAPHSC * GOC;         // 8192*128 (drug 1)
  float* cbuf  = ws + (size_t)2 * N_GRAPHSC * GOC;
  short* wt1   = (short*)(ws + (size_t)3 * N_GRAPHSC * GOC);  // 80x96
  short* wt2   = wt1 + 80 * 96;                               // 160x96
  short* wt3   = wt2 + 160 * 96;                               // 320x160
  float* pbuf  = ws + (size_t)3 * N_GRAPHSC * GOC + 37120;     // 16384x312
  float* outp  = (float*)d_out;

  pack_wt<<<dim3((80 * 96 + 255) / 256), dim3(256), 0, stream>>>(W1, wt1, FXD, FXD, 96, 80);
  pack_wt<<<dim3((160 * 96 + 255) / 256), dim3(256), 0, stream>>>(W2, wt2, FXD, F2C, 96, 160);
  pack_wt<<<dim3((320 * 160 + 255) / 256), dim3(256), 0, stream>>>(W3, wt3, F2C, F3C, 160, 320);

  dim3 dgrid(N_GRAPHSC, 2);
  drug_kernel<<<dgrid, dim3(256), 0, stream>>>(
      x1, ei1, x2, ei2, wt1, b1, wt2, b2, wt3, b3, pbuf);
  gmlp_kernel<<<dim3(2 * N_GRAPHSC / GRBK), dim3(256), 0, stream>>>(
      pbuf, Wg1, bg1, Wg2, bg2, g1buf);   // writes both g1buf and g2buf halves
  cell_kernel<<<dim3(N_GRAPHSC / RBK), dim3(256), 0, stream>>>(
      cel, Wr1, br1, Wr2, br2, Wr3, br3, cbuf);
  head_kernel<<<dim3(N_GRAPHSC / RBK), dim3(256), 0, stream>>>(
      g1buf, g2buf, cbuf, Wf1, bf1, Wf2, bf2, Wo, bo, pa, outp);
}

// Round 8
// 1028.597 us; speedup vs baseline: 1.5318x; 1.3525x over previous
//
#include <hip/hip_runtime.h>
#include <hip/hip_bf16.h>
#include <math.h>

#define N_EDGESC  1048576
#define N_GRAPHSC 8192
#define NPG 32     // nodes per graph
#define EPG 128    // edges per graph
#define FXD 78
#define F2C 156
#define F3C 312
#define GHC 156    // Wg1 out
#define GOC 128    // Wg2 out
#define HS  36     // As fp32 row stride
#define XBS 40     // Xb bf16 row stride (80 B: bank step 20 -> conflict-free)
#define HBS 168    // Hb row stride in shorts (84 dwords; m*84%32 cycles banks)
#define RBK 8      // rows per block in cell/head kernels
#define GRBK 8     // rows per block in gmlp kernel
#define NCELLB (N_GRAPHSC / RBK)   // 1024 cell blocks lead the fused grid

typedef __attribute__((ext_vector_type(8))) short short8v;   // 8 bf16 = 4 VGPR
typedef __attribute__((ext_vector_type(4))) short short4v;
typedef __attribute__((ext_vector_type(4))) float float4v;

__device__ __forceinline__ short f2bf(float x) {  // RNE truncate f32->bf16 bits
  unsigned u = __float_as_uint(x);
  u += 0x7FFFu + ((u >> 16) & 1u);
  return (short)(u >> 16);
}

// ---------------------------------------------------------------------------
// MFMA aggregation: Hb[s][f] = bf16( sum_d A[s][d] * H[d][f] ).
// Afrag = Asb rows (s-major, k=d), Bfrag = Xb rows (f-major, k=d). K=32 -> one
// MFMA per (m-tile, f-tile). Replaces the VALU a_mult (the spill site).
template<int NT>
__device__ __forceinline__ void agg_mfma(const short* __restrict__ Asb,
                                         const short* __restrict__ Xb,
                                         short* __restrict__ Hb, int t) {
  const int w = t >> 6;
  const int L = t & 63;
  const int q = L >> 4;
  const int mt = w & 1;
  const int m = mt * 16 + (L & 15);
  const short8v afrag = *(const short8v*)(Asb + m * 32 + q * 8);
  for (int nt = (w >> 1); nt < NT; nt += 2) {
    const int f = nt * 16 + (L & 15);
    const short8v bfrag = *(const short8v*)(Xb + f * XBS + q * 8);
    float4v acc = {0.f, 0.f, 0.f, 0.f};
    acc = __builtin_amdgcn_mfma_f32_16x16x32_bf16(afrag, bfrag, acc, 0, 0, 0);
#pragma unroll
    for (int i = 0; i < 4; ++i)
      Hb[(mt * 16 + q * 4 + i) * HBS + f] = f2bf(acc[i]);   // f < 160 < HBS
  }
}

// ---------------------------------------------------------------------------
// MFMA mm: D[m][f] = sum_k Hb[m][k] * Wt[f][k] (+bias, relu).
// Non-pool epilogue writes bf16 into Xb[f][node] (next layer's Bfrag).
template<int KSTEPS, int NT, int KP, int FOUT, bool POOL>
__device__ __forceinline__ void mm_mfma(const short* __restrict__ Hb,
                                        const short* __restrict__ Wt,
                                        const float* __restrict__ bias,
                                        short* __restrict__ Xout,
                                        unsigned* __restrict__ gmax, int t) {
  const int w = t >> 6;
  const int L = t & 63;
  const int q = L >> 4;
  const int mt = w & 1;                 // wave -> fixed m-tile (A-frag reuse)
  const int m = mt * 16 + (L & 15);
  short8v afrag[KSTEPS];
#pragma unroll
  for (int s = 0; s < KSTEPS; ++s)
    afrag[s] = *(const short8v*)(Hb + m * HBS + s * 32 + q * 8);
  for (int nt = (w >> 1); nt < NT; nt += 2) {
    const int f = nt * 16 + (L & 15);
    float4v acc = {0.f, 0.f, 0.f, 0.f};
#pragma unroll
    for (int s = 0; s < KSTEPS; ++s) {
      short8v bfrag = *(const short8v*)(Wt + (size_t)f * KP + s * 32 + q * 8);
      acc = __builtin_amdgcn_mfma_f32_16x16x32_bf16(afrag[s], bfrag, acc, 0, 0, 0);
    }
    if (f < FOUT) {
      float bb = bias[f];
      float o0 = fmaxf(acc[0] + bb, 0.f), o1 = fmaxf(acc[1] + bb, 0.f);
      float o2 = fmaxf(acc[2] + bb, 0.f), o3 = fmaxf(acc[3] + bb, 0.f);
      if constexpr (POOL) {
        float mx = fmaxf(fmaxf(o0, o1), fmaxf(o2, o3));
        atomicMax(&gmax[f], __float_as_uint(mx));   // relu'd >= 0 -> monotone
      } else {
        short4v o4;
        o4[0] = f2bf(o0); o4[1] = f2bf(o1); o4[2] = f2bf(o2); o4[3] = f2bf(o3);
        *(short4v*)(Xout + (size_t)f * XBS + mt * 16 + q * 4) = o4;
      }
    }
  }
}

// ---------------------------------------------------------------------------
// Weight pre-pack: Wt[f][k] = bf16(W[k][f]), zero-padded to Np x Kp.
__global__ __launch_bounds__(256)
void pack_wt(const float* __restrict__ src, short* __restrict__ dst,
             int FIN, int FOUT, int Kp, int Np) {
  int idx = blockIdx.x * 256 + threadIdx.x;
  if (idx >= Np * Kp) return;
  int f = idx / Kp, k = idx - f * Kp;
  float v = (f < FOUT && k < FIN) ? src[(size_t)k * FOUT + f] : 0.f;
  dst[idx] = f2bf(v);
}

// ---------------------------------------------------------------------------
// Fused kernel: blocks [0,1024) = cell MLP (independent, backfills drug's
// latency stalls); blocks [1024, 1024+16384) = drug GCN (one block per
// graph x drug). Shared smem buffer is the max of the two needs.
__global__ __launch_bounds__(256, 3)
void fused_kernel(const float* __restrict__ x1, const int* __restrict__ ei1,
                  const float* __restrict__ x2, const int* __restrict__ ei2,
                  const short* __restrict__ Wt1, const float* __restrict__ b1,
                  const short* __restrict__ Wt2, const float* __restrict__ b2,
                  const short* __restrict__ Wt3, const float* __restrict__ b3,
                  float* __restrict__ pbuf,
                  const float* __restrict__ cell,
                  const float* __restrict__ Wr1, const float* __restrict__ br1,
                  const float* __restrict__ Wr2, const float* __restrict__ br2,
                  const float* __restrict__ Wr3, const float* __restrict__ br3,
                  float* __restrict__ cout) {
  __shared__ __align__(16) char smem[31584];
  const int t = threadIdx.x;

  if (blockIdx.x < NCELLB) {
    // ================= cell path (R4/R6-proven body) =================
    float* U  = (float*)smem;             // 16384 B
    float* h2 = (float*)(smem + 16384);   //  8192 B
    const int R = blockIdx.x * RBK;
    const int r0 = (t & 1) * 4;
    const int f = t >> 1;

    float acc[4][4];
#pragma unroll
    for (int i = 0; i < 4; ++i)
#pragma unroll
      for (int j = 0; j < 4; ++j) acc[i][j] = 0.f;

    const int ra = t / 50, ka = t - ra * 50;
    const int i2 = t + 256;
    const int rb = i2 / 50, kb = i2 - rb * 50;
    float4 va, vb;
    va = *(const float4*)(cell + (size_t)(R + ra) * 1000 + ka * 4);
    if (t < 144) vb = *(const float4*)(cell + (size_t)(R + rb) * 1000 + kb * 4);

    for (int k0 = 0; k0 < 1000; k0 += 200) {
      __syncthreads();
      {
        int kk = ka * 4;
        U[(kk + 0) * RBK + ra] = va.x; U[(kk + 1) * RBK + ra] = va.y;
        U[(kk + 2) * RBK + ra] = va.z; U[(kk + 3) * RBK + ra] = va.w;
        if (t < 144) {
          int kk2 = kb * 4;
          U[(kk2 + 0) * RBK + rb] = vb.x; U[(kk2 + 1) * RBK + rb] = vb.y;
          U[(kk2 + 2) * RBK + rb] = vb.z; U[(kk2 + 3) * RBK + rb] = vb.w;
        }
      }
      if (k0 + 200 < 1000) {
        va = *(const float4*)(cell + (size_t)(R + ra) * 1000 + (k0 + 200) + ka * 4);
        if (t < 144)
          vb = *(const float4*)(cell + (size_t)(R + rb) * 1000 + (k0 + 200) + kb * 4);
      }
      __syncthreads();
#pragma unroll 8
      for (int k = 0; k < 200; ++k) {
        float4 h = *(const float4*)(U + k * RBK + r0);
        const float* wr = Wr1 + (size_t)(k0 + k) * 512 + f;
#pragma unroll
        for (int j = 0; j < 4; ++j) {
          float w = wr[j * 128];
          acc[0][j] = fmaf(h.x, w, acc[0][j]);
          acc[1][j] = fmaf(h.y, w, acc[1][j]);
          acc[2][j] = fmaf(h.z, w, acc[2][j]);
          acc[3][j] = fmaf(h.w, w, acc[3][j]);
        }
      }
    }
    __syncthreads();
#pragma unroll
    for (int j = 0; j < 4; ++j) {
      int ff = f + j * 128;
      float bb = br1[ff];
      float4 o;
      o.x = fmaxf(acc[0][j] + bb, 0.f); o.y = fmaxf(acc[1][j] + bb, 0.f);
      o.z = fmaxf(acc[2][j] + bb, 0.f); o.w = fmaxf(acc[3][j] + bb, 0.f);
      *(float4*)(U + ff * RBK + r0) = o;
    }
    __syncthreads();

    float a2[4][2];
#pragma unroll
    for (int i = 0; i < 4; ++i) { a2[i][0] = 0.f; a2[i][1] = 0.f; }
#pragma unroll 8
    for (int k = 0; k < 512; ++k) {
      float4 h = *(const float4*)(U + k * RBK + r0);
      const float* wr = Wr2 + (size_t)k * 256 + f;
#pragma unroll
      for (int j = 0; j < 2; ++j) {
        float w = wr[j * 128];
        a2[0][j] = fmaf(h.x, w, a2[0][j]);
        a2[1][j] = fmaf(h.y, w, a2[1][j]);
        a2[2][j] = fmaf(h.z, w, a2[2][j]);
        a2[3][j] = fmaf(h.w, w, a2[3][j]);
      }
    }
#pragma unroll
    for (int j = 0; j < 2; ++j) {
      int ff = f + j * 128;
      float bb = br2[ff];
      float4 o;
      o.x = fmaxf(a2[0][j] + bb, 0.f); o.y = fmaxf(a2[1][j] + bb, 0.f);
      o.z = fmaxf(a2[2][j] + bb, 0.f); o.w = fmaxf(a2[3][j] + bb, 0.f);
      *(float4*)(h2 + ff * RBK + r0) = o;
    }
    __syncthreads();

    float a3[4];
#pragma unroll
    for (int i = 0; i < 4; ++i) a3[i] = 0.f;
#pragma unroll 8
    for (int k = 0; k < 256; ++k) {
      float4 h = *(const float4*)(h2 + k * RBK + r0);
      float w = Wr3[(size_t)k * 128 + f];
      a3[0] = fmaf(h.x, w, a3[0]);
      a3[1] = fmaf(h.y, w, a3[1]);
      a3[2] = fmaf(h.z, w, a3[2]);
      a3[3] = fmaf(h.w, w, a3[3]);
    }
    {
      float bb = br3[f];
#pragma unroll
      for (int i = 0; i < 4; ++i)
        cout[(size_t)(R + r0 + i) * GOC + f] = a3[i] + bb;
    }
    return;
  }

  // ================= drug path =================
  short* Xb   = (short*)smem;             // [160][XBS] bf16, 12800 B
  short* Hb   = (short*)(smem + 12800);   // [32][HBS]  bf16, 10752 B
  float* As   = (float*)(smem + 23552);   // [32][HS]   fp32,  4608 B
  short* Asb  = (short*)(smem + 28160);   // [32][32]   bf16,  2048 B
  float* gbuf = (float*)(smem + 30208);   //                   1248 B
  float* deg  = (float*)(smem + 31456);   //                    128 B
  unsigned* gbufU = (unsigned*)gbuf;

  const int bid = blockIdx.x - NCELLB;
  const int gid = bid & (N_GRAPHSC - 1);
  const int drug = bid >> 13;
  const float* __restrict__ x = drug ? x2 : x1;
  const int* __restrict__ ei = drug ? ei2 : ei1;
  const int nbase = gid * NPG;

  // ---- P0: zero deg/As/Hb/gbuf/Xb-tail; load x -> bf16 Xb[f][n]
  if (t < NPG) deg[t] = 0.f;
  for (int i = t; i < NPG * HS; i += 256) As[i] = 0.f;
  for (int i = t; i < NPG * HBS / 2; i += 256) ((int*)Hb)[i] = 0;
  {
    int* xz = (int*)(Xb + FXD * XBS);     // rows [78,160) must stay zero
    for (int i = t; i < (160 - FXD) * XBS / 2; i += 256) xz[i] = 0;
  }
  for (int i = t; i < F3C; i += 256) gbufU[i] = 0u;
  const float* xg = x + (size_t)gid * (NPG * FXD);
  float4 xv[3];
#pragma unroll
  for (int j = 0; j < 3; ++j) {
    int idx = t + j * 256;
    if (idx < (NPG * FXD) / 4) xv[j] = ((const float4*)xg)[idx];
  }
  int s = 0, d = 0;
  if (t < EPG) {
    s = ei[(size_t)gid * EPG + t] - nbase;
    d = ei[(size_t)N_EDGESC + (size_t)gid * EPG + t] - nbase;
  }
#pragma unroll
  for (int j = 0; j < 3; ++j) {
    int idx = t + j * 256;
    if (idx < (NPG * FXD) / 4) {
      const float* vp = (const float*)&xv[j];
      int base = idx * 4;
#pragma unroll
      for (int jj = 0; jj < 4; ++jj) {
        int id2 = base + jj;
        int n = id2 / FXD;
        int k = id2 - n * FXD;
        Xb[k * XBS + n] = f2bf(vp[jj]);
      }
    }
  }
  __syncthreads();
  if (t < EPG) atomicAdd(&deg[s], 1.0f);
  __syncthreads();
  if (t < EPG) {
    float wgt = rsqrtf(deg[s] + 1.0f) * rsqrtf(deg[d] + 1.0f);
    atomicAdd(&As[d * HS + s], wgt);   // A[s][d]: msg d->s
  }
  if (t < NPG) atomicAdd(&As[t * HS + t], 1.0f / (deg[t] + 1.0f));
  __syncthreads();
  // convert A to bf16, s-major k-major for the agg Afrag
  for (int i = t; i < NPG * NPG; i += 256) {
    int ss = i >> 5, dd = i & 31;
    Asb[ss * 32 + dd] = f2bf(As[dd * HS + ss]);
  }
  __syncthreads();

  // ---- layer 1: agg (MFMA) -> Hb ; W1 (MFMA) -> Xb rows <78
  agg_mfma<5>(Asb, Xb, Hb, t);
  __syncthreads();
  mm_mfma<3, 5, 96, FXD, false>(Hb, Wt1, b1, Xb, nullptr, t);
  __syncthreads();
  // ---- layer 2 (rows 78,79 of Xb are zero: FOUT=78 never wrote them)
  agg_mfma<5>(Asb, Xb, Hb, t);
  __syncthreads();
  mm_mfma<3, 10, 96, F2C, false>(Hb, Wt2, b2, Xb, nullptr, t);
  __syncthreads();
  // ---- layer 3 + pool (rows 156..159 zero)
  agg_mfma<10>(Asb, Xb, Hb, t);
  __syncthreads();
  mm_mfma<5, 20, 160, F3C, true>(Hb, Wt3, b3, nullptr, gbufU, t);
  __syncthreads();

  const int p = drug * N_GRAPHSC + gid;
  for (int i = t; i < F3C; i += 256) pbuf[(size_t)p * F3C + i] = gbuf[i];
}

// ---------------------------------------------------------------------------
// Batched graph MLP: 16384 pooled rows x (312 ->relu 156 -> 128). GRBK=8.
__global__ __launch_bounds__(256, 8)
void gmlp_kernel(const float* __restrict__ pbuf,
                 const float* __restrict__ Wg1, const float* __restrict__ bg1,
                 const float* __restrict__ Wg2, const float* __restrict__ bg2,
                 float* __restrict__ gout) {
  __shared__ __align__(16) float U[F3C * GRBK];   //  9984 B
  __shared__ __align__(16) float H1[GHC * GRBK];  //  4992 B
  const int t = threadIdx.x;
  const int P = blockIdx.x * GRBK;

  for (int i = t; i < (F3C / 4) * GRBK; i += 256) {
    int r = i / (F3C / 4), c4 = i - r * (F3C / 4);
    float4 v = *(const float4*)(pbuf + (size_t)(P + r) * F3C + c4 * 4);
    int k = c4 * 4;
    U[(k + 0) * GRBK + r] = v.x; U[(k + 1) * GRBK + r] = v.y;
    U[(k + 2) * GRBK + r] = v.z; U[(k + 3) * GRBK + r] = v.w;
  }
  __syncthreads();

  const int r0 = (t & 1) * 4;
  const int f = t >> 1;
  float acc[4][2];
#pragma unroll
  for (int i = 0; i < 4; ++i) { acc[i][0] = 0.f; acc[i][1] = 0.f; }
#pragma unroll 4
  for (int k = 0; k < F3C; ++k) {
    float4 h = *(const float4*)(U + k * GRBK + r0);
    const float* wr = Wg1 + (size_t)k * GHC + f;
#pragma unroll
    for (int j = 0; j < 2; ++j) {
      if (f + j * 128 < GHC) {
        float w = wr[j * 128];
        acc[0][j] = fmaf(h.x, w, acc[0][j]);
        acc[1][j] = fmaf(h.y, w, acc[1][j]);
        acc[2][j] = fmaf(h.z, w, acc[2][j]);
        acc[3][j] = fmaf(h.w, w, acc[3][j]);
      }
    }
  }
  __syncthreads();
#pragma unroll
  for (int j = 0; j < 2; ++j) {
    int ff = f + j * 128;
    if (ff < GHC) {
      float bb = bg1[ff];
      float4 o;
      o.x = fmaxf(acc[0][j] + bb, 0.f); o.y = fmaxf(acc[1][j] + bb, 0.f);
      o.z = fmaxf(acc[2][j] + bb, 0.f); o.w = fmaxf(acc[3][j] + bb, 0.f);
      *(float4*)(H1 + ff * GRBK + r0) = o;
    }
  }
  __syncthreads();

  float a2[4];
#pragma unroll
  for (int i = 0; i < 4; ++i) a2[i] = 0.f;
#pragma unroll 4
  for (int k = 0; k < GHC; ++k) {
    float4 h = *(const float4*)(H1 + k * GRBK + r0);
    float w = Wg2[(size_t)k * GOC + f];
    a2[0] = fmaf(h.x, w, a2[0]);
    a2[1] = fmaf(h.y, w, a2[1]);
    a2[2] = fmaf(h.z, w, a2[2]);
    a2[3] = fmaf(h.w, w, a2[3]);
  }
  {
    float bb = bg2[f];
#pragma unroll
    for (int i = 0; i < 4; ++i)
      gout[(size_t)(P + r0 + i) * GOC + f] = a2[i] + bb;
  }
}

// ---------------------------------------------------------------------------
// Head (R4-proven): 8 rows/block, unroll 8 on the two big k-loops.
__global__ __launch_bounds__(256, 4)
void head_kernel(const float* __restrict__ g1, const float* __restrict__ g2,
                 const float* __restrict__ cc,
                 const float* __restrict__ Wf1, const float* __restrict__ bf1,
                 const float* __restrict__ Wf2, const float* __restrict__ bf2,
                 const float* __restrict__ Wo, const float* __restrict__ bo,
                 const float* __restrict__ pa, float* __restrict__ out) {
  __shared__ __align__(16) float U[512 * RBK];   // 16384 B
  __shared__ __align__(16) float h2[128 * RBK];  //  4096 B
  __shared__ float ssq[RBK];
  __shared__ float scal[RBK];
  __shared__ float red[256];

  const int t = threadIdx.x;
  const int R = blockIdx.x * RBK;
  if (t < RBK) ssq[t] = 0.f;
  __syncthreads();
  for (int i = t; i < 96 * RBK; i += 256) {
    int r = i / 96, qq = i - r * 96;
    int col = qq * 4;
    const float* src;
    int c2;
    if (col < 128)      { src = g1; c2 = col; }
    else if (col < 256) { src = g2; c2 = col - 128; }
    else                { src = cc; c2 = col - 256; }
    float4 v = *(const float4*)(src + (size_t)(R + r) * GOC + c2);
    U[(col + 0) * RBK + r] = v.x; U[(col + 1) * RBK + r] = v.y;
    U[(col + 2) * RBK + r] = v.z; U[(col + 3) * RBK + r] = v.w;
    atomicAdd(&ssq[r], v.x * v.x + v.y * v.y + v.z * v.z + v.w * v.w);
  }
  __syncthreads();
  if (t < RBK) scal[t] = 1.0f / fmaxf(sqrtf(ssq[t]), 1e-12f);
  __syncthreads();

  const float a = pa[0];
  const int r0 = (t & 1) * 4;
  const int f = t >> 1;

  float acc[4][4];
#pragma unroll
  for (int i = 0; i < 4; ++i)
#pragma unroll
    for (int j = 0; j < 4; ++j) acc[i][j] = 0.f;
#pragma unroll 8
  for (int k = 0; k < 384; ++k) {
    float4 h = *(const float4*)(U + k * RBK + r0);
    const float* wr = Wf1 + (size_t)k * 512 + f;
#pragma unroll
    for (int j = 0; j < 4; ++j) {
      float w = wr[j * 128];
      acc[0][j] = fmaf(h.x, w, acc[0][j]);
      acc[1][j] = fmaf(h.y, w, acc[1][j]);
      acc[2][j] = fmaf(h.z, w, acc[2][j]);
      acc[3][j] = fmaf(h.w, w, acc[3][j]);
    }
  }
  __syncthreads();
#pragma unroll
  for (int j = 0; j < 4; ++j) {
    int ff = f + j * 128;
    float bb = bf1[ff];
    float4 o;
    float v0 = acc[0][j] * scal[r0 + 0] + bb; o.x = v0 >= 0.f ? v0 : a * v0;
    float v1 = acc[1][j] * scal[r0 + 1] + bb; o.y = v1 >= 0.f ? v1 : a * v1;
    float v2 = acc[2][j] * scal[r0 + 2] + bb; o.z = v2 >= 0.f ? v2 : a * v2;
    float v3 = acc[3][j] * scal[r0 + 3] + bb; o.w = v3 >= 0.f ? v3 : a * v3;
    *(float4*)(U + ff * RBK + r0) = o;
  }
  __syncthreads();

  float a2[4];
#pragma unroll
  for (int i = 0; i < 4; ++i) a2[i] = 0.f;
#pragma unroll 8
  for (int k = 0; k < 512; ++k) {
    float4 h = *(const float4*)(U + k * RBK + r0);
    float w = Wf2[(size_t)k * 128 + f];
    a2[0] = fmaf(h.x, w, a2[0]);
    a2[1] = fmaf(h.y, w, a2[1]);
    a2[2] = fmaf(h.z, w, a2[2]);
    a2[3] = fmaf(h.w, w, a2[3]);
  }
  {
    float bb = bf2[f];
#pragma unroll
    for (int i = 0; i < 4; ++i) {
      float v = a2[i] + bb;
      v = v >= 0.f ? v : a * v;
      h2[f * RBK + (r0 + i)] = v;
    }
  }
  __syncthreads();

  {
    int rr = t >> 5, kp = t & 31;
    float p = 0.f;
#pragma unroll
    for (int jj = 0; jj < 4; ++jj) {
      int k = kp + 32 * jj;
      p = fmaf(h2[k * RBK + rr], Wo[k], p);
    }
    red[t] = p;
  }
  __syncthreads();
  if (t < RBK) {
    float ssum = bo[0];
#pragma unroll
    for (int i = 0; i < 32; ++i) ssum += red[t * 32 + i];
    out[R + t] = 1.0f / (1.0f + expf(-ssum));
  }
}

// ---------------------------------------------------------------------------
extern "C" void kernel_launch(void* const* d_in, const int* in_sizes, int n_in,
                              void* d_out, int out_size, void* d_ws, size_t ws_size,
                              hipStream_t stream) {
  const float* x1  = (const float*)d_in[0];
  const int*   ei1 = (const int*)d_in[1];
  const float* x2  = (const float*)d_in[2];
  const int*   ei2 = (const int*)d_in[3];
  const float* cel = (const float*)d_in[4];
  const float* W1  = (const float*)d_in[7];
  const float* b1  = (const float*)d_in[8];
  const float* W2  = (const float*)d_in[9];
  const float* b2  = (const float*)d_in[10];
  const float* W3  = (const float*)d_in[11];
  const float* b3  = (const float*)d_in[12];
  const float* Wg1 = (const float*)d_in[13];
  const float* bg1 = (const float*)d_in[14];
  const float* Wg2 = (const float*)d_in[15];
  const float* bg2 = (const float*)d_in[16];
  const float* Wr1 = (const float*)d_in[17];
  const float* br1 = (const float*)d_in[18];
  const float* Wr2 = (const float*)d_in[19];
  const float* br2 = (const float*)d_in[20];
  const float* Wr3 = (const float*)d_in[21];
  const float* br3 = (const float*)d_in[22];
  const float* Wf1 = (const float*)d_in[23];
  const float* bf1 = (const float*)d_in[24];
  const float* Wf2 = (const float*)d_in[25];
  const float* bf2 = (const float*)d_in[26];
  const float* Wo  = (const float*)d_in[27];
  const float* bo  = (const float*)d_in[28];
  const float* pa  = (const float*)d_in[29];

  float* ws    = (float*)d_ws;
  float* g1buf = ws;                                   // 16384x128 (both drugs)
  float* g2buf = ws + (size_t)N_GRAPHSC * GOC;
  float* cbuf  = ws + (size_t)2 * N_GRAPHSC * GOC;
  short* wt1   = (short*)(ws + (size_t)3 * N_GRAPHSC * GOC);  // 80x96
  short* wt2   = wt1 + 80 * 96;                               // 160x96
  short* wt3   = wt2 + 160 * 96;                               // 320x160
  float* pbuf  = ws + (size_t)3 * N_GRAPHSC * GOC + 37120;     // 16384x312
  float* outp  = (float*)d_out;

  pack_wt<<<dim3((80 * 96 + 255) / 256), dim3(256), 0, stream>>>(W1, wt1, FXD, FXD, 96, 80);
  pack_wt<<<dim3((160 * 96 + 255) / 256), dim3(256), 0, stream>>>(W2, wt2, FXD, F2C, 96, 160);
  pack_wt<<<dim3((320 * 160 + 255) / 256), dim3(256), 0, stream>>>(W3, wt3, F2C, F3C, 160, 320);

  fused_kernel<<<dim3(NCELLB + 2 * N_GRAPHSC), dim3(256), 0, stream>>>(
      x1, ei1, x2, ei2, wt1, b1, wt2, b2, wt3, b3, pbuf,
      cel, Wr1, br1, Wr2, br2, Wr3, br3, cbuf);
  gmlp_kernel<<<dim3(2 * N_GRAPHSC / GRBK), dim3(256), 0, stream>>>(
      pbuf, Wg1, bg1, Wg2, bg2, g1buf);   // writes g1buf and g2buf halves
  head_kernel<<<dim3(N_GRAPHSC / RBK), dim3(256), 0, stream>>>(
      g1buf, g2buf, cbuf, Wf1, bf1, Wf2, bf2, Wo, bo, pa, outp);
}